// Round 15
// baseline (160.635 us; speedup 1.0000x reference)
//
#include <hip/hip_runtime.h>
#include <math.h>

#define CLASSES 8
#define SIZE 512
#define ISZ 512
#define CSZ 512
#define BATCH 64
#define CMS 4
#define NBUCKET 16
#define LR 0.01f
#define WCLIP 5.0f
#define WSTRIDE 516    // W gather: banks 4*(idx+off)%32 -> worst 2-way (free)

// ---------------- kernel 1: pack (R4/R11 verbatim) ----------------
// Lt    (B, C*I)      : Lt[b*4096 + ci]                  = logits[ci, b]
// Lpk   (C*I/4, B, 4) : Lpk[(ci>>2)*256 + 4*b + (ci&3)]  = logits[ci, b]
// ctxT4 (D/4, B, 4)   : ctxT4[(d>>2)*256 + 4*b + (d&3)]  = context[b, d]
__global__ __launch_bounds__(256) void pack_pre(
    const float* __restrict__ logits,    // (C*I, B)
    const float* __restrict__ context,   // (B, D)
    float* __restrict__ Lt,
    float* __restrict__ Lpk,
    float* __restrict__ ctxT4)
{
    __shared__ float t[64][65];
    const int bid  = blockIdx.x;
    const int lane = threadIdx.x & 63;
    const int w    = threadIdx.x >> 6;
    if (bid < 64) {
        const int r0 = bid << 6;                     // ci base
        #pragma unroll
        for (int rep = 0; rep < 16; ++rep) {
            int rr = w * 16 + rep;
            t[rr][lane] = logits[(size_t)(r0 + rr) * 64 + lane];
        }
        __syncthreads();
        const int ci = r0 + lane;
        #pragma unroll
        for (int rep = 0; rep < 16; ++rep) {
            int b = w * 16 + rep;
            float v = t[lane][b];
            Lt[(size_t)b * 4096 + ci] = v;
            Lpk[(size_t)(ci >> 2) * 256 + 4 * b + (ci & 3)] = v;
        }
    } else {
        const int c0 = (bid - 64) << 6;              // d base
        #pragma unroll
        for (int rep = 0; rep < 16; ++rep) {
            int rr = w * 16 + rep;                   // b
            t[rr][lane] = context[(size_t)rr * 512 + c0 + lane];
        }
        __syncthreads();
        #pragma unroll
        for (int rep = 0; rep < 16; ++rep) {
            int dd = c0 + w * 16 + rep;              // d
            ctxT4[(size_t)(dd >> 2) * 256 + 4 * lane + (dd & 3)] = t[lane][w * 16 + rep];
        }
    }
}

// ---------------- kernel 2: distances -> bucket idx (R8/R11 verbatim revert) ----------------
// Proven passing + ~35 us at grid 4096 (R14's grid-1024 variant was latency-
// exposed: serial acc chain needs deep wave oversubscription). Rules
// (R1/R3/R10 blowups): cm operand WAVE-UNIFORM (readfirstlane -> s_load);
// ctx operand LANE-CONSECUTIVE (lane=b, coalesced). Single-acc 4-term chain.
// Do NOT re-derive this loop (R5/R6 knife-edge post-mortem).
__global__ __launch_bounds__(256, 8) void dist_kernel(
    const float* __restrict__ cmaps,     // (C, S, 4, 512)
    const float* __restrict__ cbias,     // (C, S, 4, 1)
    const float* __restrict__ ctxT4,     // packed context
    unsigned char* __restrict__ idxOut)  // (4096, 64)
{
    __shared__ int bits[CMS * BATCH];

    const int tid  = threadIdx.x;
    const int cs   = blockIdx.x;       // c*SIZE + s
    const int lane = tid & 63;
    const int wv   = tid >> 6;
    const int k    = __builtin_amdgcn_readfirstlane(wv);   // wave-uniform

    const float4* cmg = (const float4*)(cmaps + ((size_t)cs * CMS + k) * CSZ);
    {
        const float4* ct4 = (const float4*)ctxT4 + lane;
        float acc = 0.f;
        #pragma unroll 4
        for (int d4 = 0; d4 < 128; ++d4) {
            float4 cm4 = cmg[d4];                    // uniform -> s_load_dwordx4
            float4 cv  = ct4[(size_t)d4 * 64];
            acc += cm4.x * cv.x + cm4.y * cv.y + cm4.z * cv.z + cm4.w * cv.w;
        }
        float bias = cbias[(size_t)cs * CMS + k];
        bits[k * BATCH + lane] = (acc > bias) ? 1 : 0;
    }
    __syncthreads();

    if (wv == 0) {
        int idx_b = bits[lane] | (bits[BATCH + lane] << 1) |
                    (bits[2 * BATCH + lane] << 2) | (bits[3 * BATCH + lane] << 3);
        idxOut[(size_t)cs * BATCH + lane] = (unsigned char)idx_b;
    }
}

// ---------------- kernel 3: bucket-half blocks (2 per cs), 8 blocks/CU ----------------
// Block (cs, h) owns buckets [8h, 8h+8): stages 8 W rows (16.5 KB LDS), gathers
// for lanes whose idx_b is in its half (exec-masked; Lpk traffic unchanged),
// computes out/diff for those lanes (summation tree identical to R8 -> out
// bit-identical), updates + stores its 8 rows. No registers held across
// barriers -> no spills (R13/R14 lesson: WRITE inflation = scratch traffic).
__global__ __launch_bounds__(256, 8) void gln_bch(
    const float* __restrict__ target,   // (C, B)
    const float* __restrict__ weights,  // (C, S, 16, 512)
    const unsigned char* __restrict__ idxIn,
    const float* __restrict__ Lt,       // (B, C*I)
    const float* __restrict__ Lpk,      // (C*I/4, B, 4)
    float* __restrict__ out,            // (C, S, B)
    float* __restrict__ outW)           // (C, S, 16, 512)
{
    __shared__ float Wl[8 * WSTRIDE];   // 16.5 KB: this half's 8 rows, padded
    __shared__ float partial[4 * BATCH];
    __shared__ float diff_l[BATCH];
    __shared__ int   blast_l[8];

    const int tid   = threadIdx.x;
    const int bid   = blockIdx.x;
    const int cs    = bid >> 1;
    const int h     = bid & 1;
    const int rbase = h << 3;           // buckets [rbase, rbase+8)
    const int c     = cs >> 9;
    const int lane  = tid & 63;
    const int wv    = tid >> 6;

    // stage this half's W rows (8 x 512 f32 = 1024 f4), coalesced
    const float4* gW = (const float4*)(weights + (size_t)cs * (NBUCKET * ISZ) + rbase * ISZ);
    #pragma unroll
    for (int it = 0; it < 4; ++it) {
        int f = tid + it * 256;
        float4 v = gW[f];
        *(float4*)&Wl[(f >> 7) * WSTRIDE + (f & 127) * 4] = v;
    }

    const int idx_b = idxIn[(size_t)cs * BATCH + lane];
    const int rloc  = idx_b - rbase;
    const bool act  = (rloc >= 0) && (rloc < 8);

    // last-writer per local bucket (ballots full-wave; idx_b identical across waves)
    #pragma unroll
    for (int j = 0; j < 8; ++j) {
        unsigned long long m = __ballot(idx_b == rbase + j);
        if (tid == 0) blast_l[j] = m ? (63 - __clzll(m)) : -1;   // np last-write-wins
    }
    __syncthreads();

    // gather-dot for active lanes; wave wv covers i in [128*wv, 128*wv+128)
    {
        float acc = 0.f;
        if (act) {
            const float4* Lp4 = (const float4*)Lpk;
            const int base4 = (c * 128 + wv * 32) * 64 + lane;
            const int wb    = rloc * WSTRIDE + wv * 128;
            #pragma unroll 4
            for (int d4 = 0; d4 < 32; ++d4) {
                float4 w4 = *(const float4*)&Wl[wb + d4 * 4];
                float4 l4 = Lp4[(size_t)base4 + d4 * 64];
                acc += w4.x * l4.x + w4.y * l4.y + w4.z * l4.z + w4.w * l4.w;
            }
        }
        partial[wv * BATCH + lane] = acc;
    }
    __syncthreads();

    // wave 0: out + diff for this half's lanes only
    if (wv == 0) {
        float s = partial[lane] + partial[BATCH + lane] +
                  partial[2 * BATCH + lane] + partial[3 * BATCH + lane];
        if (act) {
            const float hi = 4.595119850134589f;    // logit(0.99)
            float oc = fminf(fmaxf(s, -hi), hi);
            out[(size_t)cs * BATCH + lane] = oc;
            float sig = 1.f / (1.f + expf(-oc));
            diff_l[lane] = LR * (sig - target[c * BATCH + lane]);
        }
    }
    __syncthreads();

    // update this half's 8 rows from LDS; stream out coalesced
    float* gO = outW + (size_t)cs * (NBUCKET * ISZ) + rbase * ISZ;
    const float* LtC = Lt + (size_t)c * ISZ;
    #pragma unroll
    for (int it = 0; it < 4; ++it) {
        int f    = tid + it * 256;
        int row  = f >> 7;
        int col4 = f & 127;
        float4 w4 = *(const float4*)&Wl[row * WSTRIDE + col4 * 4];
        int bl = blast_l[row];
        float4 r = w4;
        if (bl >= 0) {
            float coef = diff_l[bl];
            float4 l4  = ((const float4*)(LtC + (size_t)bl * 4096))[col4];
            r.x = fminf(fmaxf(w4.x - coef * l4.x, -WCLIP), WCLIP);
            r.y = fminf(fmaxf(w4.y - coef * l4.y, -WCLIP), WCLIP);
            r.z = fminf(fmaxf(w4.z - coef * l4.z, -WCLIP), WCLIP);
            r.w = fminf(fmaxf(w4.w - coef * l4.w, -WCLIP), WCLIP);
        }
        ((float4*)gO)[f] = r;
    }
}

extern "C" void kernel_launch(void* const* d_in, const int* in_sizes, int n_in,
                              void* d_out, int out_size, void* d_ws, size_t ws_size,
                              hipStream_t stream) {
    const float* logits  = (const float*)d_in[0];  // (8,512,64)
    const float* context = (const float*)d_in[1];  // (64,512)
    const float* target  = (const float*)d_in[2];  // (8,64)
    const float* cmaps   = (const float*)d_in[3];  // (8,512,4,512)
    const float* cbias   = (const float*)d_in[4];  // (8,512,4,1)
    const float* weights = (const float*)d_in[5];  // (8,512,16,512)

    float* out  = (float*)d_out;                        // (8,512,64)
    float* outW = out + (size_t)CLASSES * SIZE * BATCH; // (8,512,16,512)

    float* Lt    = (float*)d_ws;            // 1 MB
    float* Lpk   = Lt + 262144;             // 1 MB
    float* ctxT4 = Lpk + 262144;            // 128 KB
    unsigned char* idxb = (unsigned char*)(ctxT4 + 32768);   // 256 KB

    pack_pre<<<72, 256, 0, stream>>>(logits, context, Lt, Lpk, ctxT4);
    dist_kernel<<<CLASSES * SIZE, 256, 0, stream>>>(cmaps, cbias, ctxT4, idxb);
    gln_bch<<<CLASSES * SIZE * 2, 256, 0, stream>>>(target, weights, idxb, Lt, Lpk, out, outW);
}

// Round 17
// 147.227 us; speedup vs baseline: 1.0911x; 1.0911x over previous
//
#include <hip/hip_runtime.h>
#include <math.h>

#define CLASSES 8
#define SIZE 512
#define ISZ 512
#define CSZ 512
#define BATCH 64
#define CMS 4
#define NBUCKET 16
#define LR 0.01f
#define WCLIP 5.0f
#define WSTRIDE 516    // W gather: banks 4*(idx+off)%32 -> worst 2-way (free)

// ---------------- kernel 1: pack (R4/R11 verbatim) ----------------
// Lt    (B, C*I)      : Lt[b*4096 + ci]                  = logits[ci, b]
// Lpk   (C*I/4, B, 4) : Lpk[(ci>>2)*256 + 4*b + (ci&3)]  = logits[ci, b]
// ctxT4 (D/4, B, 4)   : ctxT4[(d>>2)*256 + 4*b + (d&3)]  = context[b, d]
__global__ __launch_bounds__(256) void pack_pre(
    const float* __restrict__ logits,    // (C*I, B)
    const float* __restrict__ context,   // (B, D)
    float* __restrict__ Lt,
    float* __restrict__ Lpk,
    float* __restrict__ ctxT4)
{
    __shared__ float t[64][65];
    const int bid  = blockIdx.x;
    const int lane = threadIdx.x & 63;
    const int w    = threadIdx.x >> 6;
    if (bid < 64) {
        const int r0 = bid << 6;                     // ci base
        #pragma unroll
        for (int rep = 0; rep < 16; ++rep) {
            int rr = w * 16 + rep;
            t[rr][lane] = logits[(size_t)(r0 + rr) * 64 + lane];
        }
        __syncthreads();
        const int ci = r0 + lane;
        #pragma unroll
        for (int rep = 0; rep < 16; ++rep) {
            int b = w * 16 + rep;
            float v = t[lane][b];
            Lt[(size_t)b * 4096 + ci] = v;
            Lpk[(size_t)(ci >> 2) * 256 + 4 * b + (ci & 3)] = v;
        }
    } else {
        const int c0 = (bid - 64) << 6;              // d base
        #pragma unroll
        for (int rep = 0; rep < 16; ++rep) {
            int rr = w * 16 + rep;                   // b
            t[rr][lane] = context[(size_t)rr * 512 + c0 + lane];
        }
        __syncthreads();
        #pragma unroll
        for (int rep = 0; rep < 16; ++rep) {
            int dd = c0 + w * 16 + rep;              // d
            ctxT4[(size_t)(dd >> 2) * 256 + 4 * lane + (dd & 3)] = t[lane][w * 16 + rep];
        }
    }
}

// ---------------- kernel 2: distances -> bucket idx (R8/R11 verbatim, FROZEN) ----------------
// Proven passing + ~35 us. Rules (R1/R3/R10 blowups): cm operand WAVE-UNIFORM
// (readfirstlane -> s_load); ctx operand LANE-CONSECUTIVE (lane=b, coalesced).
// Single-acc 4-term chain, unroll 4. Knife-edge ledger: single-acc chains pass
// (R8, R14); multi-acc chains flip one bucket (R5/R6/R16 -> absmax 6.7e-3).
// DO NOT restructure this kernel further.
__global__ __launch_bounds__(256, 8) void dist_kernel(
    const float* __restrict__ cmaps,     // (C, S, 4, 512)
    const float* __restrict__ cbias,     // (C, S, 4, 1)
    const float* __restrict__ ctxT4,     // packed context
    unsigned char* __restrict__ idxOut)  // (4096, 64)
{
    __shared__ int bits[CMS * BATCH];

    const int tid  = threadIdx.x;
    const int cs   = blockIdx.x;       // c*SIZE + s
    const int lane = tid & 63;
    const int wv   = tid >> 6;
    const int k    = __builtin_amdgcn_readfirstlane(wv);   // wave-uniform

    const float4* cmg = (const float4*)(cmaps + ((size_t)cs * CMS + k) * CSZ);
    {
        const float4* ct4 = (const float4*)ctxT4 + lane;
        float acc = 0.f;
        #pragma unroll 4
        for (int d4 = 0; d4 < 128; ++d4) {
            float4 cm4 = cmg[d4];                    // uniform -> s_load_dwordx4
            float4 cv  = ct4[(size_t)d4 * 64];
            acc += cm4.x * cv.x + cm4.y * cv.y + cm4.z * cv.z + cm4.w * cv.w;
        }
        float bias = cbias[(size_t)cs * CMS + k];
        bits[k * BATCH + lane] = (acc > bias) ? 1 : 0;
    }
    __syncthreads();

    if (wv == 0) {
        int idx_b = bits[lane] | (bits[BATCH + lane] << 1) |
                    (bits[2 * BATCH + lane] << 2) | (bits[3 * BATCH + lane] << 3);
        idxOut[(size_t)cs * BATCH + lane] = (unsigned char)idx_b;
    }
}

// ---------------- kernel 3: software-pipelined 2-cs gather-dot + update ----------------
// T14 async-stage: issue cs B's W loads under cs A's gather; stage B into LDS
// while wave0 finishes A's softmax; A's update stores overlap B's gather.
// Per-cs arithmetic/indexing is R8-verbatim (no downstream comparisons -> no
// knife-edge exposure). VGPR ~90 (wregA+wregB) under (256,4) cap 128, no spill.
__global__ __launch_bounds__(256, 4) void gln_bc(
    const float* __restrict__ target,   // (C, B)
    const float* __restrict__ weights,  // (C, S, 16, 512)
    const unsigned char* __restrict__ idxIn,
    const float* __restrict__ Lt,
    const float* __restrict__ Lpk,
    float* __restrict__ out,            // (C, S, B)
    float* __restrict__ outW)           // (C, S, 16, 512)
{
    __shared__ float Wl[NBUCKET * WSTRIDE];   // 33 KB padded rows (reused A then B)
    __shared__ float partial[4 * BATCH];
    __shared__ float diff_l[BATCH];
    __shared__ int   blastA[NBUCKET];
    __shared__ int   blastB[NBUCKET];

    const int tid  = threadIdx.x;
    const int csA  = blockIdx.x * 2;
    const int csB  = csA + 1;
    const int c    = csA >> 9;          // csA even -> csB same class
    const int lane = tid & 63;
    const int wv   = tid >> 6;

    // prologue: A's W slice -> regs
    float4 wregA[8];
    const float4* gWA = (const float4*)(weights + (size_t)csA * (NBUCKET * ISZ));
    #pragma unroll
    for (int it = 0; it < 8; ++it) wregA[it] = gWA[tid + it * 256];

    const int idxA = idxIn[(size_t)csA * BATCH + lane];
    const int idxB = idxIn[(size_t)csB * BATCH + lane];

    // last-writers for both cs (wave wv owns buckets 4wv..4wv+3; np last-write-wins)
    #pragma unroll
    for (int jj = 0; jj < 4; ++jj) {
        int j = (wv << 2) + jj;
        unsigned long long mA = __ballot(idxA == j);
        unsigned long long mB = __ballot(idxB == j);
        if (lane == 0) {
            blastA[j] = mA ? (63 - __clzll(mA)) : -1;
            blastB[j] = mB ? (63 - __clzll(mB)) : -1;
        }
    }

    // stage A -> LDS
    #pragma unroll
    for (int it = 0; it < 8; ++it) {
        int f = tid + it * 256;
        *(float4*)&Wl[(f >> 7) * WSTRIDE + (f & 127) * 4] = wregA[it];
    }
    __syncthreads();

    // issue B's W loads now: ~900cy HBM latency hides under gather A
    float4 wregB[8];
    const float4* gWB = (const float4*)(weights + (size_t)csB * (NBUCKET * ISZ));
    #pragma unroll
    for (int it = 0; it < 8; ++it) wregB[it] = gWB[tid + it * 256];

    // gather A (R8-verbatim): wave wv covers i in [128*wv, 128*wv+128)
    {
        const float4* Lp4 = (const float4*)Lpk;
        const int base4 = (c * 128 + wv * 32) * 64 + lane;
        const int wb    = idxA * WSTRIDE + wv * 128;
        float acc = 0.f;
        #pragma unroll 4
        for (int d4 = 0; d4 < 32; ++d4) {
            float4 w4 = *(const float4*)&Wl[wb + d4 * 4];
            float4 l4 = Lp4[(size_t)base4 + d4 * 64];
            acc += w4.x * l4.x + w4.y * l4.y + w4.z * l4.z + w4.w * l4.w;
        }
        partial[wv * BATCH + lane] = acc;
    }
    __syncthreads();

    // stage B into Wl (gather A complete) ; wave0 additionally: out/diff A
    #pragma unroll
    for (int it = 0; it < 8; ++it) {
        int f = tid + it * 256;
        *(float4*)&Wl[(f >> 7) * WSTRIDE + (f & 127) * 4] = wregB[it];
    }
    if (wv == 0) {
        float s = partial[lane] + partial[BATCH + lane] +
                  partial[2 * BATCH + lane] + partial[3 * BATCH + lane];
        const float hi = 4.595119850134589f;    // logit(0.99)
        float oc = fminf(fmaxf(s, -hi), hi);
        out[(size_t)csA * BATCH + lane] = oc;
        float sig = 1.f / (1.f + expf(-oc));
        diff_l[lane] = LR * (sig - target[c * BATCH + lane]);
    }
    __syncthreads();

    const float* LtC = Lt + (size_t)c * ISZ;

    // update A (HBM stores overlap gather B below)
    {
        float* gO = outW + (size_t)csA * (NBUCKET * ISZ);
        #pragma unroll
        for (int it = 0; it < 8; ++it) {
            int f    = tid + it * 256;
            int row  = f >> 7;
            int col4 = f & 127;
            float4 w4 = wregA[it];
            int bl = blastA[row];
            float4 r = w4;
            if (bl >= 0) {
                float coef = diff_l[bl];
                float4 l4  = ((const float4*)(LtC + (size_t)bl * 4096))[col4];
                r.x = fminf(fmaxf(w4.x - coef * l4.x, -WCLIP), WCLIP);
                r.y = fminf(fmaxf(w4.y - coef * l4.y, -WCLIP), WCLIP);
                r.z = fminf(fmaxf(w4.z - coef * l4.z, -WCLIP), WCLIP);
                r.w = fminf(fmaxf(w4.w - coef * l4.w, -WCLIP), WCLIP);
            }
            ((float4*)gO)[f] = r;
        }
    }

    // gather B
    {
        const float4* Lp4 = (const float4*)Lpk;
        const int base4 = (c * 128 + wv * 32) * 64 + lane;
        const int wb    = idxB * WSTRIDE + wv * 128;
        float acc = 0.f;
        #pragma unroll 4
        for (int d4 = 0; d4 < 32; ++d4) {
            float4 w4 = *(const float4*)&Wl[wb + d4 * 4];
            float4 l4 = Lp4[(size_t)base4 + d4 * 64];
            acc += w4.x * l4.x + w4.y * l4.y + w4.z * l4.z + w4.w * l4.w;
        }
        partial[wv * BATCH + lane] = acc;
    }
    __syncthreads();

    // wave0: out/diff B
    if (wv == 0) {
        float s = partial[lane] + partial[BATCH + lane] +
                  partial[2 * BATCH + lane] + partial[3 * BATCH + lane];
        const float hi = 4.595119850134589f;
        float oc = fminf(fmaxf(s, -hi), hi);
        out[(size_t)csB * BATCH + lane] = oc;
        float sig = 1.f / (1.f + expf(-oc));
        diff_l[lane] = LR * (sig - target[c * BATCH + lane]);
    }
    __syncthreads();

    // update B
    {
        float* gO = outW + (size_t)csB * (NBUCKET * ISZ);
        #pragma unroll
        for (int it = 0; it < 8; ++it) {
            int f    = tid + it * 256;
            int row  = f >> 7;
            int col4 = f & 127;
            float4 w4 = wregB[it];
            int bl = blastB[row];
            float4 r = w4;
            if (bl >= 0) {
                float coef = diff_l[bl];
                float4 l4  = ((const float4*)(LtC + (size_t)bl * 4096))[col4];
                r.x = fminf(fmaxf(w4.x - coef * l4.x, -WCLIP), WCLIP);
                r.y = fminf(fmaxf(w4.y - coef * l4.y, -WCLIP), WCLIP);
                r.z = fminf(fmaxf(w4.z - coef * l4.z, -WCLIP), WCLIP);
                r.w = fminf(fmaxf(w4.w - coef * l4.w, -WCLIP), WCLIP);
            }
            ((float4*)gO)[f] = r;
        }
    }
}

extern "C" void kernel_launch(void* const* d_in, const int* in_sizes, int n_in,
                              void* d_out, int out_size, void* d_ws, size_t ws_size,
                              hipStream_t stream) {
    const float* logits  = (const float*)d_in[0];  // (8,512,64)
    const float* context = (const float*)d_in[1];  // (64,512)
    const float* target  = (const float*)d_in[2];  // (8,64)
    const float* cmaps   = (const float*)d_in[3];  // (8,512,4,512)
    const float* cbias   = (const float*)d_in[4];  // (8,512,4,1)
    const float* weights = (const float*)d_in[5];  // (8,512,16,512)

    float* out  = (float*)d_out;                        // (8,512,64)
    float* outW = out + (size_t)CLASSES * SIZE * BATCH; // (8,512,16,512)

    float* Lt    = (float*)d_ws;            // 1 MB
    float* Lpk   = Lt + 262144;             // 1 MB
    float* ctxT4 = Lpk + 262144;            // 128 KB
    unsigned char* idxb = (unsigned char*)(ctxT4 + 32768);   // 256 KB

    pack_pre<<<72, 256, 0, stream>>>(logits, context, Lt, Lpk, ctxT4);
    dist_kernel<<<CLASSES * SIZE, 256, 0, stream>>>(cmaps, cbias, ctxT4, idxb);
    gln_bc<<<CLASSES * SIZE / 2, 256, 0, stream>>>(target, weights, idxb, Lt, Lpk, out, outW);
}